// Round 6
// baseline (221.797 us; speedup 1.0000x reference)
//
#include <hip/hip_runtime.h>
#include <math.h>

#define NN 1024
#define DD 64
#define HH 256
#define TEMP_INV 10.0f
#define KCH 64
#define NKC 4

// ws layout (floats):
//   xpbT   [HH][NN]      : xp + b1, transposed (k-major)   1 MB
//   ypT    [HH][NN]      : yp, transposed                  1 MB
//   pscore [NKC][NN][NN] : partial scores per k-chunk     16 MB
//   acc    [2]           : sum(lse), sum(pos)
//   tick   [17] (u32)    : per-i-chunk tickets [0..15], final ticket [16]

__global__ __launch_bounds__(256)
void k1_proj(const float* __restrict__ x, const float* __restrict__ y,
             const float* __restrict__ W1, const float* __restrict__ b1,
             float* __restrict__ xpbT, float* __restrict__ ypT,
             float* __restrict__ acc, unsigned int* __restrict__ tick)
{
    const int tid = threadIdx.x;
    if (blockIdx.x == 0) {          // re-arm tickets/accumulators every call
        if (tid < 17) tick[tid] = 0u;
        else if (tid == 17) { acc[0] = 0.f; acc[1] = 0.f; }
    }
    const int i0 = blockIdx.x * 2;
    float ax0 = 0.f, ax1 = 0.f, ay0 = 0.f, ay1 = 0.f;
    #pragma unroll 8
    for (int kk = 0; kk < DD; ++kk) {
        const float wx = W1[kk * HH + tid];
        const float wy = W1[(DD + kk) * HH + tid];
        ax0 = fmaf(x[i0 * DD + kk],       wx, ax0);
        ax1 = fmaf(x[(i0 + 1) * DD + kk], wx, ax1);
        ay0 = fmaf(y[i0 * DD + kk],       wy, ay0);
        ay1 = fmaf(y[(i0 + 1) * DD + kk], wy, ay1);
    }
    const float b1t = b1[tid];
    *(float2*)&xpbT[tid * NN + i0] = make_float2(ax0 + b1t, ax1 + b1t);
    *(float2*)&ypT[tid * NN + i0]  = make_float2(ay0, ay1);
}

// 64x64 tile, one 64-k chunk per block; grid (16 j, 16 i, 4 k) = 1024 blocks
// = 4 blocks/CU = 4 waves/SIMD. Last finisher of each i-chunk (64 blocks)
// does that chunk's LSE + pos; last chunk writes the scalar. No grid sync.
__global__ __launch_bounds__(256, 4)
void k2_scores(const float* __restrict__ xpbT, const float* __restrict__ ypT,
               const float* __restrict__ w2, const float* __restrict__ b2,
               float* __restrict__ pscore, float* __restrict__ acc,
               unsigned int* __restrict__ tick, float* __restrict__ out)
{
    __shared__ float ys[KCH][64];   // 16 KB
    __shared__ float xs[KCH][64];   // 16 KB
    __shared__ float2 red[256];     // 2 KB (finalize only)
    __shared__ unsigned int s_old;
    const int tid = threadIdx.x;
    const int bj = blockIdx.x, bi = blockIdx.y, bk = blockIdx.z;
    const int i0 = bi * 64, j0 = bj * 64, k0 = bk * KCH;
    const int lr = tid >> 4;    // 0..15
    const int lc = tid & 15;    // 0..15

    #pragma unroll
    for (int g = 0; g < 4; ++g) {
        const int kk = lr + g * 16;
        *(float4*)&ys[kk][lc * 4] = *(const float4*)&ypT[(k0 + kk) * NN + i0 + lc * 4];
        *(float4*)&xs[kk][lc * 4] = *(const float4*)&xpbT[(k0 + kk) * NN + j0 + lc * 4];
    }
    __syncthreads();

    float pa[4][4];
    #pragma unroll
    for (int p = 0; p < 4; ++p)
        #pragma unroll
        for (int q = 0; q < 4; ++q) pa[p][q] = 0.f;

    #pragma unroll 8
    for (int kk = 0; kk < KCH; ++kk) {
        const float w2k = w2[k0 + kk];               // uniform -> scalar load
        const float4 yv4 = *(const float4*)&ys[kk][lr * 4];
        const float4 xv4 = *(const float4*)&xs[kk][lc * 4];
        const float yv[4] = {yv4.x, yv4.y, yv4.z, yv4.w};
        const float xv[4] = {xv4.x, xv4.y, xv4.z, xv4.w};
        #pragma unroll
        for (int p = 0; p < 4; ++p)
            #pragma unroll
            for (int q = 0; q < 4; ++q)
                pa[p][q] = fmaf(fmaxf(yv[p] + xv[q], 0.f), w2k, pa[p][q]);
    }

    float* dst = pscore + (size_t)bk * NN * NN;
    #pragma unroll
    for (int p = 0; p < 4; ++p)
        *(float4*)&dst[(i0 + lr * 4 + p) * NN + j0 + lc * 4] =
            make_float4(pa[p][0], pa[p][1], pa[p][2], pa[p][3]);

    // ---- fan-in: last of the 64 blocks for i-chunk bi finalizes it ----
    __threadfence();
    __syncthreads();
    if (tid == 0) s_old = atomicAdd(&tick[bi], 1u);
    __syncthreads();
    if (s_old != 63u) return;
    __threadfence();

    const float bb = b2[0];
    const int r = tid >> 2, sub = tid & 3;       // 64 rows x 4 col-quarters
    const int grow = i0 + r;
    const int cbase = sub * 256;
    const float* P = pscore + (size_t)grow * NN + cbase;
    float M = -1e30f, E = 0.f, myp = 0.f;
    #pragma unroll 2
    for (int cc = 0; cc < 256; cc += 4) {
        const float4 a0 = *(const float4*)&P[cc];
        const float4 a1 = *(const float4*)&P[(size_t)1 * NN * NN + cc];
        const float4 a2 = *(const float4*)&P[(size_t)2 * NN * NN + cc];
        const float4 a3 = *(const float4*)&P[(size_t)3 * NN * NN + cc];
        const float s0 = (a0.x + a1.x + a2.x + a3.x + bb) * TEMP_INV;
        const float s1 = (a0.y + a1.y + a2.y + a3.y + bb) * TEMP_INV;
        const float s2 = (a0.z + a1.z + a2.z + a3.z + bb) * TEMP_INV;
        const float s3 = (a0.w + a1.w + a2.w + a3.w + bb) * TEMP_INV;
        const int dq = grow - (cbase + cc);
        if (dq >= 0 && dq < 4)
            myp = (dq == 0) ? s0 : (dq == 1) ? s1 : (dq == 2) ? s2 : s3;
        const float m4 = fmaxf(fmaxf(s0, s1), fmaxf(s2, s3));
        const float Mn = fmaxf(M, m4);
        E = E * __expf(M - Mn) + __expf(s0 - Mn) + __expf(s1 - Mn) +
            __expf(s2 - Mn) + __expf(s3 - Mn);
        M = Mn;
    }
    #pragma unroll
    for (int mk = 1; mk <= 2; mk <<= 1) {        // merge the 4 col-quarters
        const float Mo = __shfl_xor(M, mk);
        const float Eo = __shfl_xor(E, mk);
        const float Mn = fmaxf(M, Mo);
        E = E * __expf(M - Mn) + Eo * __expf(Mo - Mn);
        M = Mn;
        myp += __shfl_xor(myp, mk);
    }
    red[tid] = make_float2((sub == 0) ? (M + logf(E)) : 0.f,
                           (sub == 0) ? myp : 0.f);
    __syncthreads();
    for (int s = 128; s > 0; s >>= 1) {
        if (tid < s) {
            const float2 o = red[tid + s];
            float2 m2 = red[tid];
            m2.x += o.x; m2.y += o.y;
            red[tid] = m2;
        }
        __syncthreads();
    }
    if (tid == 0) {
        atomicAdd(&acc[0], red[0].x);
        atomicAdd(&acc[1], red[0].y);
        __threadfence();
        const unsigned int old2 = atomicAdd(&tick[16], 1u);
        if (old2 == 15u) {                        // all 16 chunks accumulated
            __threadfence();
            const float aL = __hip_atomic_load(&acc[0], __ATOMIC_RELAXED,
                                               __HIP_MEMORY_SCOPE_AGENT);
            const float aP = __hip_atomic_load(&acc[1], __ATOMIC_RELAXED,
                                               __HIP_MEMORY_SCOPE_AGENT);
            out[0] = aL / (float)NN - logf((float)NN) - aP / (float)NN;
        }
    }
}

extern "C" void kernel_launch(void* const* d_in, const int* in_sizes, int n_in,
                              void* d_out, int out_size, void* d_ws, size_t ws_size,
                              hipStream_t stream)
{
    const float* x  = (const float*)d_in[0];
    const float* y  = (const float*)d_in[1];
    const float* W1 = (const float*)d_in[2];
    const float* b1 = (const float*)d_in[3];
    const float* w2 = (const float*)d_in[4];
    const float* b2 = (const float*)d_in[5];
    float* out = (float*)d_out;

    float* ws     = (float*)d_ws;
    float* xpbT   = ws;                               // 256*1024
    float* ypT    = xpbT + HH * NN;                   // 256*1024
    float* pscore = ypT + HH * NN;                    // 4*1024*1024
    float* acc    = pscore + (size_t)NKC * NN * NN;   // 2
    unsigned int* tick = (unsigned int*)(acc + 2);    // 17

    hipLaunchKernelGGL(k1_proj, dim3(NN / 2), dim3(256), 0, stream,
                       x, y, W1, b1, xpbT, ypT, acc, tick);
    hipLaunchKernelGGL(k2_scores, dim3(16, 16, NKC), dim3(256), 0, stream,
                       xpbT, ypT, w2, b2, pscore, acc, tick, out);
}

// Round 7
// 41.256 us; speedup vs baseline: 5.3761x; 5.3761x over previous
//
#include <hip/hip_runtime.h>
#include <math.h>

#define NN 1024
#define DD 64
#define HH 256
#define TEMP_INV 10.0f
#define KCH 64
#define NCH (HH / KCH)   // 4 k-chunks, all inside one block

// ws layout (floats):
//   xpbT [HH][NN]  : xp + b1, transposed (k-major)  1 MB
//   ypT  [HH][NN]  : yp, transposed                 1 MB
//   pmax [16][NN]  : per (j-chunk, row) partial max
//   psum [16][NN]  : per (j-chunk, row) partial sum(exp)
//   pos  [NN]

__global__ __launch_bounds__(256)
void k1_proj(const float* __restrict__ x, const float* __restrict__ y,
             const float* __restrict__ W1, const float* __restrict__ b1,
             float* __restrict__ xpbT, float* __restrict__ ypT)
{
    const int tid = threadIdx.x;        // h index 0..255
    const int i0 = blockIdx.x * 2;      // 2 rows per block -> 512 blocks
    float ax0 = 0.f, ax1 = 0.f, ay0 = 0.f, ay1 = 0.f;
    #pragma unroll 8
    for (int kk = 0; kk < DD; ++kk) {
        const float wx = W1[kk * HH + tid];
        const float wy = W1[(DD + kk) * HH + tid];
        ax0 = fmaf(x[i0 * DD + kk],       wx, ax0);
        ax1 = fmaf(x[(i0 + 1) * DD + kk], wx, ax1);
        ay0 = fmaf(y[i0 * DD + kk],       wy, ay0);
        ay1 = fmaf(y[(i0 + 1) * DD + kk], wy, ay1);
    }
    const float b1t = b1[tid];
    *(float2*)&xpbT[tid * NN + i0] = make_float2(ax0 + b1t, ax1 + b1t);
    *(float2*)&ypT[tid * NN + i0]  = make_float2(ay0, ay1);
}

// 64x64 tile, FULL K=256 (4 chunks of 64, double-buffered LDS, 1 barrier per
// chunk). 512 threads = 8 waves -> 256 blocks = 1 block/CU = 2 waves/SIMD.
// Per-thread 4x2 tile: float4 y-rows (broadcast reads) x float2 x-cols.
// Block epilogue: partial LSE over its 64 cols -> pmax/psum[16][NN] + pos.
__global__ __launch_bounds__(512)
void k2_scores(const float* __restrict__ xpbT, const float* __restrict__ ypT,
               const float* __restrict__ w2, const float* __restrict__ b2,
               float* __restrict__ pmax, float* __restrict__ psum,
               float* __restrict__ pos)
{
    __shared__ float ys[2][KCH][64];   // 32 KB
    __shared__ float xs[2][KCH][64];   // 32 KB
    __shared__ float w2s[HH];          // 1 KB
    const int t  = threadIdx.x;
    const int bj = blockIdx.x, bi = blockIdx.y;
    const int i0 = bi * 64, j0 = bj * 64;
    const int rr = t >> 5;   // 0..15 -> rows i0 + 4rr .. +3
    const int cc = t & 31;   // 0..31 -> cols j0 + 2cc, +1

    if (t < HH) w2s[t] = w2[t];

    // stage chunk c into buffer buf: 1024 float4 per array, 2 per thread
    #define STAGE(c, buf)                                                      \
    {                                                                          \
        const int k0s = (c) * KCH;                                             \
        _Pragma("unroll")                                                      \
        for (int h = 0; h < 2; ++h) {                                          \
            const int f  = t + h * 512;                                        \
            const int r  = f >> 4;                                             \
            const int c4 = (f & 15) * 4;                                       \
            *(float4*)&ys[buf][r][c4] =                                        \
                *(const float4*)&ypT[(k0s + r) * NN + i0 + c4];                \
            *(float4*)&xs[buf][r][c4] =                                        \
                *(const float4*)&xpbT[(k0s + r) * NN + j0 + c4];               \
        }                                                                      \
    }

    float a00=0.f,a01=0.f, a10=0.f,a11=0.f, a20=0.f,a21=0.f, a30=0.f,a31=0.f;

    STAGE(0, 0);
    __syncthreads();
    for (int c = 0; c < NCH; ++c) {
        if (c + 1 < NCH) STAGE(c + 1, (c + 1) & 1);
        const int k0 = c * KCH;
        const int cur = c & 1;
        #pragma unroll 8
        for (int kk = 0; kk < KCH; ++kk) {
            const float w2k = w2s[k0 + kk];
            const float4 yv = *(const float4*)&ys[cur][kk][rr * 4];
            const float2 xv = *(const float2*)&xs[cur][kk][cc * 2];
            a00 = fmaf(fmaxf(yv.x + xv.x, 0.f), w2k, a00);
            a01 = fmaf(fmaxf(yv.x + xv.y, 0.f), w2k, a01);
            a10 = fmaf(fmaxf(yv.y + xv.x, 0.f), w2k, a10);
            a11 = fmaf(fmaxf(yv.y + xv.y, 0.f), w2k, a11);
            a20 = fmaf(fmaxf(yv.z + xv.x, 0.f), w2k, a20);
            a21 = fmaf(fmaxf(yv.z + xv.y, 0.f), w2k, a21);
            a30 = fmaf(fmaxf(yv.w + xv.x, 0.f), w2k, a30);
            a31 = fmaf(fmaxf(yv.w + xv.y, 0.f), w2k, a31);
        }
        __syncthreads();
    }
    #undef STAGE

    const float bb = b2[0];
    float s[4][2];
    s[0][0] = (a00 + bb) * TEMP_INV; s[0][1] = (a01 + bb) * TEMP_INV;
    s[1][0] = (a10 + bb) * TEMP_INV; s[1][1] = (a11 + bb) * TEMP_INV;
    s[2][0] = (a20 + bb) * TEMP_INV; s[2][1] = (a21 + bb) * TEMP_INV;
    s[3][0] = (a30 + bb) * TEMP_INV; s[3][1] = (a31 + bb) * TEMP_INV;

    // diagonal -> pos
    if (bi == bj) {
        #pragma unroll
        for (int p = 0; p < 4; ++p)
            #pragma unroll
            for (int q = 0; q < 2; ++q)
                if (rr * 4 + p == cc * 2 + q)
                    pos[i0 + rr * 4 + p] = s[p][q];
    }

    // per-row partial (max, sum-exp) over this block's 64 cols.
    // lane = (rr&1)*32 + cc; xor masks 1..16 reduce over cc within the wave.
    float m[4], e[4];
    #pragma unroll
    for (int p = 0; p < 4; ++p) {
        m[p] = fmaxf(s[p][0], s[p][1]);
        e[p] = __expf(s[p][0] - m[p]) + __expf(s[p][1] - m[p]);
    }
    #pragma unroll
    for (int mk = 16; mk >= 1; mk >>= 1) {
        #pragma unroll
        for (int p = 0; p < 4; ++p) {
            const float mo = __shfl_xor(m[p], mk);
            const float eo = __shfl_xor(e[p], mk);
            const float mn = fmaxf(m[p], mo);
            e[p] = e[p] * __expf(m[p] - mn) + eo * __expf(mo - mn);
            m[p] = mn;
        }
    }
    if (cc == 0) {
        #pragma unroll
        for (int p = 0; p < 4; ++p) {
            const int row = i0 + rr * 4 + p;
            pmax[bj * NN + row] = m[p];
            psum[bj * NN + row] = e[p];
        }
    }
}

// Single block, 1024 threads: one row per thread. Merge 16 j-chunk partials,
// add pos, block-reduce, write the scalar.
__global__ __launch_bounds__(1024)
void k3_final(const float* __restrict__ pmax, const float* __restrict__ psum,
              const float* __restrict__ pos, float* __restrict__ out)
{
    __shared__ float2 red[1024];
    const int tid = threadIdx.x;      // row
    float M = pmax[tid], E = psum[tid];
    #pragma unroll
    for (int jc = 1; jc < 16; ++jc) {
        const float Mo = pmax[jc * NN + tid];
        const float Eo = psum[jc * NN + tid];
        const float Mn = fmaxf(M, Mo);
        E = E * __expf(M - Mn) + Eo * __expf(Mo - Mn);
        M = Mn;
    }
    red[tid] = make_float2(M + logf(E), pos[tid]);
    __syncthreads();
    for (int s = 512; s > 0; s >>= 1) {
        if (tid < s) {
            const float2 o = red[tid + s];
            float2 m2 = red[tid];
            m2.x += o.x; m2.y += o.y;
            red[tid] = m2;
        }
        __syncthreads();
    }
    if (tid == 0)
        out[0] = red[0].x / (float)NN - logf((float)NN) - red[0].y / (float)NN;
}

extern "C" void kernel_launch(void* const* d_in, const int* in_sizes, int n_in,
                              void* d_out, int out_size, void* d_ws, size_t ws_size,
                              hipStream_t stream)
{
    const float* x  = (const float*)d_in[0];
    const float* y  = (const float*)d_in[1];
    const float* W1 = (const float*)d_in[2];
    const float* b1 = (const float*)d_in[3];
    const float* w2 = (const float*)d_in[4];
    const float* b2 = (const float*)d_in[5];
    float* out = (float*)d_out;

    float* ws   = (float*)d_ws;
    float* xpbT = ws;                 // 256*1024
    float* ypT  = xpbT + HH * NN;     // 256*1024
    float* pmax = ypT + HH * NN;      // 16*1024
    float* psum = pmax + 16 * NN;     // 16*1024
    float* pos  = psum + 16 * NN;     // 1024

    hipLaunchKernelGGL(k1_proj, dim3(NN / 2), dim3(256), 0, stream,
                       x, y, W1, b1, xpbT, ypT);
    hipLaunchKernelGGL(k2_scores, dim3(16, 16), dim3(512), 0, stream,
                       xpbT, ypT, w2, b2, pmax, psum, pos);
    hipLaunchKernelGGL(k3_final, dim3(1), dim3(1024), 0, stream,
                       pmax, psum, pos, out);
}